// Round 10
// baseline (244.026 us; speedup 1.0000x reference)
//
#include <hip/hip_runtime.h>
#include <math.h>

constexpr int T = 1024;
constexpr int H = 2048;
constexpr int I = 1024;
constexpr int E = 16;
constexpr int K = 2;
constexpr int L = 4;
constexpr int R = 16;
constexpr int P = T * K;        // 2048 (token,k) pairs
constexpr int MT_MAX = 32;      // max m-tiles (BM=128)
constexpr int G_CVT = T * H / (256 * 8);   // 1024 convert blocks
constexpr int GRID_MEGA = MT_MAX * 32 + P + MT_MAX * 64;  // 5120 tickets max

typedef __attribute__((ext_vector_type(8))) short bf16x8;
typedef __attribute__((ext_vector_type(4))) float f32x4;

__device__ inline unsigned short f2bf(float f) {
  unsigned u = __builtin_bit_cast(unsigned, f);
  u = (u + 0x7FFFu + ((u >> 16) & 1u)) >> 16;
  return (unsigned short)u;
}

__device__ inline bf16x8 pack8(f32x4 a, f32x4 b) {
  bf16x8 v;
  v[0] = (short)f2bf(a[0]); v[1] = (short)f2bf(a[1]);
  v[2] = (short)f2bf(a[2]); v[3] = (short)f2bf(a[3]);
  v[4] = (short)f2bf(b[0]); v[5] = (short)f2bf(b[1]);
  v[6] = (short)f2bf(b[2]); v[7] = (short)f2bf(b[3]);
  return v;
}

// LDS rows of 64 bf16 (128B); XOR swizzle (0 bank conflicts, verified r2-r9)
__device__ inline void st8(unsigned short* s, int r, int c, bf16x8 v) {
  int byte = ((r << 6) + c) * 2;
  byte ^= (r & 7) << 4;
  *reinterpret_cast<bf16x8*>(reinterpret_cast<char*>(s) + byte) = v;
}
__device__ inline bf16x8 ld8(const unsigned short* s, int r, int c) {
  int byte = ((r << 6) + c) * 2;
  byte ^= (r & 7) << 4;
  return *reinterpret_cast<const bf16x8*>(reinterpret_cast<const char*>(s) + byte);
}

// ---------------------------------------------------------------------------
// Launch 1: cvt+zero (blocks 0..G_CVT-1) || routing + flag init (block G_CVT)
// pairs sorted by expert (primary) and lora id (secondary) for L2 locality
// ---------------------------------------------------------------------------
__global__ __launch_bounds__(256) void prep_kernel(
    const float* __restrict__ x, unsigned short* __restrict__ xb,
    float* __restrict__ out,
    const int* __restrict__ topk_ids, const float* __restrict__ topk_w,
    const int* __restrict__ lora_idx,
    int* __restrict__ eoff, int* __restrict__ pair_t,
    float* __restrict__ pair_w, int* __restrict__ pair_e,
    int* __restrict__ tile_e, int* __restrict__ tile_m0, int* __restrict__ ntiles,
    int* __restrict__ q, int* __restrict__ done) {
  const int tid = threadIdx.x;
  if (blockIdx.x < G_CVT) {
    const int i = (blockIdx.x * 256 + tid) * 8;
    f32x4 a = *reinterpret_cast<const f32x4*>(x + i);
    f32x4 b = *reinterpret_cast<const f32x4*>(x + i + 4);
    *reinterpret_cast<bf16x8*>(xb + i) = pack8(a, b);
    const f32x4 z = {0.f, 0.f, 0.f, 0.f};
    *reinterpret_cast<f32x4*>(out + i) = z;
    *reinterpret_cast<f32x4*>(out + i + 4) = z;
    return;
  }
  // routing block: count per (e,l) bucket, prefix, scatter
  __shared__ int cnt2[E * L];
  __shared__ int off2[E * L + 1];
  __shared__ int cur2[E * L];
  __shared__ int ecnt[E];
  if (tid == 0) *q = 0;
  if (tid < 32) done[tid] = 0;
  if (tid < E * L) cnt2[tid] = 0;
  __syncthreads();
  for (int p = tid; p < P; p += 256) {
    const int e = topk_ids[p];
    int l = lora_idx[p / K];
    if (l < 0) l = 0;                      // bucket only; correctness unaffected
    atomicAdd(&cnt2[e * L + l], 1);
  }
  __syncthreads();
  if (tid == 0) {
    off2[0] = 0;
    for (int b = 0; b < E * L; ++b) off2[b + 1] = off2[b] + cnt2[b];
    int nt = 0;
    for (int e = 0; e < E; ++e) {
      const int c = off2[(e + 1) * L] - off2[e * L];
      ecnt[e] = c;
      for (int m0 = 0; m0 < c; m0 += 128) {
        tile_e[nt] = e;
        tile_m0[nt] = m0;
        ++nt;
      }
    }
    *ntiles = nt;
  }
  __syncthreads();
  if (tid < E * L) cur2[tid] = off2[tid];
  if (tid <= E) eoff[tid] = off2[tid * L];
  __syncthreads();
  for (int p = tid; p < P; p += 256) {
    const int e = topk_ids[p];
    int l = lora_idx[p / K];
    if (l < 0) l = 0;
    const int pos = atomicAdd(&cur2[e * L + l], 1);
    pair_t[pos] = p / K;
    pair_w[pos] = topk_w[p];
    pair_e[pos] = e;
  }
}

// ---------------------------------------------------------------------------
// Launch 2: mega kernel — one ticket per block from atomic counter.
// tickets: [gemm1 tiles (n1) | lora pairs (P) | gemm2 tiles (n2)]
// gemm2 gates on done[mt]==32 (device-scope acquire; producer releases).
// Deadlock-free: gemm2 tickets issue only after all gemm1 tickets were popped
// by already-resident blocks that never wait.
// ---------------------------------------------------------------------------
__global__ __launch_bounds__(256) void moe_mega(
    const unsigned short* xb, const float* w1, const float* w2,
    const int* eoff, const int* pair_t, const float* pair_w, const int* pair_e,
    const int* tile_e, const int* tile_m0, const int* ntiles,
    unsigned short* act,
    const float* x, const float* lora_a, const float* lora_b,
    const int* lora_idx, const int* lora_ranks, const float* scalings,
    float* out, int* q, int* done) {
  __shared__ __align__(16) char smem[24576];
  __shared__ int sh_item;
  const int tid = threadIdx.x;
  const int nt = *ntiles;
  const int n1 = nt * 32;
  const int total = n1 + P + nt * 64;

  if (tid == 0) sh_item = atomicAdd(q, 1);
  __syncthreads();
  const int item = sh_item;
  if (item >= total) return;

  if (item < n1) {
    // ---- gemm1 tile: BM=128 x BN=32 x BK=64 ----
    const int mt = item >> 5;
    const int it = item & 31;
    const int e = tile_e[mt];
    const int m0 = tile_m0[mt];
    const int beg = eoff[e];
    const int cnt = eoff[e + 1] - beg;
    const int i0 = it * 32;

    unsigned short* sX = (unsigned short*)smem;            // 128x64 = 16KB
    unsigned short* sG = (unsigned short*)(smem + 16384);  // 32x64  = 4KB
    unsigned short* sU = (unsigned short*)(smem + 20480);  // 32x64  = 4KB

    const int xr = tid >> 1, xc = (tid & 1) * 32;
    const int gr = tid >> 3, gc = (tid & 7) * 8;

    const int rm = m0 + xr;
    const int tok = (rm < cnt) ? pair_t[beg + rm] : -1;
    const unsigned short* xrow = xb + (size_t)(tok < 0 ? 0 : tok) * H + xc;
    const float* grow = w1 + ((size_t)e * (2 * I) + i0 + gr) * H + gc;
    const float* urow = grow + (size_t)I * H;

    const int lane = tid & 63, wid = tid >> 6;
    const int wm = wid << 5;
    const int fr = lane & 15, fq = lane >> 4;

    f32x4 ag[2][2], au[2][2];
#pragma unroll
    for (int a = 0; a < 2; ++a)
#pragma unroll
      for (int b = 0; b < 2; ++b) {
        ag[a][b] = {0.f, 0.f, 0.f, 0.f};
        au[a][b] = {0.f, 0.f, 0.f, 0.f};
      }

    bf16x8 rx[4];
    f32x4 rg[2], ru[2];
    const bf16x8 zero8 = {0, 0, 0, 0, 0, 0, 0, 0};

    auto LOAD = [&](int kk) {
      if (tok >= 0) {
#pragma unroll
        for (int s = 0; s < 4; ++s)
          rx[s] = *reinterpret_cast<const bf16x8*>(xrow + kk + s * 8);
      } else {
#pragma unroll
        for (int s = 0; s < 4; ++s) rx[s] = zero8;
      }
#pragma unroll
      for (int s = 0; s < 2; ++s) {
        rg[s] = *reinterpret_cast<const f32x4*>(grow + kk + s * 4);
        ru[s] = *reinterpret_cast<const f32x4*>(urow + kk + s * 4);
      }
    };

    constexpr int NT = H / 64;
    LOAD(0);
    for (int t = 0; t < NT; ++t) {
      const bf16x8 wg = pack8(rg[0], rg[1]);
      const bf16x8 wu = pack8(ru[0], ru[1]);
      __syncthreads();
      st8(sX, xr, xc + 0, rx[0]); st8(sX, xr, xc + 8, rx[1]);
      st8(sX, xr, xc + 16, rx[2]); st8(sX, xr, xc + 24, rx[3]);
      st8(sG, gr, gc, wg);
      st8(sU, gr, gc, wu);
      if (t + 1 < NT) LOAD((t + 1) * 64);
      __syncthreads();
#pragma unroll
      for (int kb = 0; kb < 2; ++kb) {
        const int k8 = (kb << 5) + (fq << 3);
        bf16x8 af[2], gf[2], uf[2];
#pragma unroll
        for (int mi = 0; mi < 2; ++mi) af[mi] = ld8(sX, wm + (mi << 4) + fr, k8);
#pragma unroll
        for (int nj = 0; nj < 2; ++nj) {
          gf[nj] = ld8(sG, (nj << 4) + fr, k8);
          uf[nj] = ld8(sU, (nj << 4) + fr, k8);
        }
#pragma unroll
        for (int mi = 0; mi < 2; ++mi)
#pragma unroll
          for (int nj = 0; nj < 2; ++nj) {
            ag[mi][nj] = __builtin_amdgcn_mfma_f32_16x16x32_bf16(af[mi], gf[nj], ag[mi][nj], 0, 0, 0);
            au[mi][nj] = __builtin_amdgcn_mfma_f32_16x16x32_bf16(af[mi], uf[nj], au[mi][nj], 0, 0, 0);
          }
      }
    }

#pragma unroll
    for (int mi = 0; mi < 2; ++mi)
#pragma unroll
      for (int q2 = 0; q2 < 4; ++q2) {
        const int m = m0 + wm + (mi << 4) + (fq << 2) + q2;
        if (m >= cnt) continue;
#pragma unroll
        for (int nj = 0; nj < 2; ++nj) {
          const float g = ag[mi][nj][q2];
          const float u = au[mi][nj][q2];
          const float s = g / (1.f + __expf(-g));
          act[(size_t)(beg + m) * I + i0 + (nj << 4) + fr] = f2bf(s * u);
        }
      }
    // publish: stores drained by syncthreads; agent release + count
    __syncthreads();
    if (tid == 0) {
      __threadfence();
      atomicAdd(&done[mt], 1);
    }
  } else if (item < n1 + P) {
    // ---- lora pair ----
    const int p = item - n1;
    const int t = pair_t[p];
    const int e = pair_e[p];
    const int l = lora_idx[t];
    if (l < 0) return;
    int rank = lora_ranks[l];
    if (rank < 1) rank = 1;
    const float sc = scalings[l];
    float* a_sh = (float*)smem;
    const int wave = tid >> 6, lane = tid & 63;
    const float4* xv = reinterpret_cast<const float4*>(x + (size_t)t * H);
    const float* Ab = lora_a + (size_t)(l * E + e) * R * H;
#pragma unroll
    for (int q2 = 0; q2 < 4; ++q2) {
      const int r = (wave << 2) | q2;
      const float4* Av = reinterpret_cast<const float4*>(Ab + (size_t)r * H);
      float s = 0.f;
#pragma unroll
      for (int it2 = 0; it2 < H / 256; ++it2) {
        const int h4 = it2 * 64 + lane;
        const float4 xx = xv[h4];
        const float4 aa = Av[h4];
        s += xx.x * aa.x + xx.y * aa.y + xx.z * aa.z + xx.w * aa.w;
      }
#pragma unroll
      for (int off = 32; off; off >>= 1) s += __shfl_xor(s, off);
      if (lane == 0) a_sh[r] = (r < rank) ? s * sc : 0.f;
    }
    __syncthreads();
    const float* Bb = lora_b + (size_t)(l * E + e) * H * R;
    for (int h = tid; h < H; h += 256) {
      const float4* Bv = reinterpret_cast<const float4*>(Bb + (size_t)h * R);
      float d = 0.f;
#pragma unroll
      for (int r4 = 0; r4 < 4; ++r4) {
        const float4 bb = Bv[r4];
        d += a_sh[r4 * 4 + 0] * bb.x + a_sh[r4 * 4 + 1] * bb.y +
             a_sh[r4 * 4 + 2] * bb.z + a_sh[r4 * 4 + 3] * bb.w;
      }
      atomicAdd(out + (size_t)t * H + h, d);
    }
  } else {
    // ---- gemm2 tile: BM=128 x BN=32 x BK=64 ----
    const int g = item - n1 - P;
    const int mt = g >> 6;
    const int ht = g & 63;
    // gate: all 32 gemm1 tiles of this mt done (device-scope acquire)
    while (__hip_atomic_load(&done[mt], __ATOMIC_ACQUIRE, __HIP_MEMORY_SCOPE_AGENT) < 32)
      __builtin_amdgcn_s_sleep(8);
    __syncthreads();

    const int e = tile_e[mt];
    const int m0 = tile_m0[mt];
    const int beg = eoff[e];
    const int cnt = eoff[e + 1] - beg;
    const int h0 = ht * 32;

    unsigned short* sA = (unsigned short*)smem;            // 128x64 = 16KB
    unsigned short* sB = (unsigned short*)(smem + 16384);  // 32x64  = 4KB

    const int ar = tid >> 1, ac = (tid & 1) * 32;
    const int br = tid >> 3, bc = (tid & 7) * 8;

    const bool av = (m0 + ar) < cnt;
    const unsigned short* arow = act + (size_t)(beg + (av ? m0 + ar : 0)) * I + ac;
    const float* brow = w2 + ((size_t)e * H + h0 + br) * I + bc;

    const int lane = tid & 63, wid = tid >> 6;
    const int wm = wid << 5;
    const int fr = lane & 15, fq = lane >> 4;

    f32x4 acc[2][2];
#pragma unroll
    for (int a = 0; a < 2; ++a)
#pragma unroll
      for (int b = 0; b < 2; ++b) acc[a][b] = {0.f, 0.f, 0.f, 0.f};

    bf16x8 ra[4];
    f32x4 rb[2];

    auto LOAD = [&](int kk) {
#pragma unroll
      for (int s = 0; s < 4; ++s)
        ra[s] = *reinterpret_cast<const bf16x8*>(arow + kk + s * 8);
#pragma unroll
      for (int s = 0; s < 2; ++s)
        rb[s] = *reinterpret_cast<const f32x4*>(brow + kk + s * 4);
    };

    constexpr int NT2 = I / 64;
    LOAD(0);
    for (int t = 0; t < NT2; ++t) {
      const bf16x8 wb = pack8(rb[0], rb[1]);
      __syncthreads();
      st8(sA, ar, ac + 0, ra[0]); st8(sA, ar, ac + 8, ra[1]);
      st8(sA, ar, ac + 16, ra[2]); st8(sA, ar, ac + 24, ra[3]);
      st8(sB, br, bc, wb);
      if (t + 1 < NT2) LOAD((t + 1) * 64);
      __syncthreads();
#pragma unroll
      for (int kb = 0; kb < 2; ++kb) {
        const int k8 = (kb << 5) + (fq << 3);
        bf16x8 af[2], bf[2];
#pragma unroll
        for (int mi = 0; mi < 2; ++mi) af[mi] = ld8(sA, wm + (mi << 4) + fr, k8);
#pragma unroll
        for (int nj = 0; nj < 2; ++nj) bf[nj] = ld8(sB, (nj << 4) + fr, k8);
#pragma unroll
        for (int mi = 0; mi < 2; ++mi)
#pragma unroll
          for (int nj = 0; nj < 2; ++nj)
            acc[mi][nj] = __builtin_amdgcn_mfma_f32_16x16x32_bf16(af[mi], bf[nj], acc[mi][nj], 0, 0, 0);
      }
    }

#pragma unroll
    for (int mi = 0; mi < 2; ++mi)
#pragma unroll
      for (int q2 = 0; q2 < 4; ++q2) {
        const int m = m0 + wm + (mi << 4) + (fq << 2) + q2;
        if (m >= cnt) continue;
        const int tt = pair_t[beg + m];
        const float w = pair_w[beg + m];
#pragma unroll
        for (int nj = 0; nj < 2; ++nj)
          atomicAdd(out + (size_t)tt * H + h0 + (nj << 4) + fr, w * acc[mi][nj][q2]);
      }
  }
}

extern "C" void kernel_launch(void* const* d_in, const int* in_sizes, int n_in,
                              void* d_out, int out_size, void* d_ws, size_t ws_size,
                              hipStream_t stream) {
  const float* x          = (const float*)d_in[0];
  const int*   topk_ids   = (const int*)d_in[1];
  const float* topk_w     = (const float*)d_in[2];
  const int*   lora_idx   = (const int*)d_in[3];
  const int*   lora_ranks = (const int*)d_in[4];
  const float* scalings   = (const float*)d_in[5];
  const float* w1         = (const float*)d_in[6];
  const float* w2         = (const float*)d_in[7];
  const float* lora_a     = (const float*)d_in[8];
  const float* lora_b     = (const float*)d_in[9];
  float* out = (float*)d_out;

  char* ws = (char*)d_ws;
  int*   eoff    = (int*)(ws);             // 17 ints
  int*   ntiles  = (int*)(ws + 96);
  int*   q       = (int*)(ws + 128);
  int*   done    = (int*)(ws + 256);       // 32 ints
  int*   tile_e  = (int*)(ws + 384);       // 32 ints
  int*   tile_m0 = (int*)(ws + 512);       // 32 ints
  int*   pair_t  = (int*)(ws + 1024);
  int*   pair_e  = (int*)(ws + 1024 + 4 * P);
  float* pair_w  = (float*)(ws + 1024 + 8 * P);
  unsigned short* xb  = (unsigned short*)(ws + 32768);                      // 4MB
  unsigned short* act = (unsigned short*)(ws + 32768 + (size_t)T * H * 2);  // 4MB

  prep_kernel<<<G_CVT + 1, 256, 0, stream>>>(x, xb, out, topk_ids, topk_w, lora_idx,
                                             eoff, pair_t, pair_w, pair_e, tile_e,
                                             tile_m0, ntiles, q, done);
  moe_mega<<<GRID_MEGA, 256, 0, stream>>>(xb, w1, w2, eoff, pair_t, pair_w, pair_e,
                                          tile_e, tile_m0, ntiles, act, x, lora_a,
                                          lora_b, lora_idx, lora_ranks, scalings,
                                          out, q, done);
}

// Round 11
// 187.181 us; speedup vs baseline: 1.3037x; 1.3037x over previous
//
#include <hip/hip_runtime.h>
#include <math.h>

constexpr int T = 1024;
constexpr int H = 2048;
constexpr int I = 1024;
constexpr int E = 16;
constexpr int K = 2;
constexpr int L = 4;
constexpr int R = 16;
constexpr int P = T * K;        // 2048 (token,k) pairs
constexpr int MT_MAX = 48;      // max m-tiles at BM=64: sum ceil(cnt/64) <= 32+16
constexpr int G_CVT = T * H / (256 * 8);   // 1024 convert blocks
constexpr int G1 = MT_MAX * 32;            // 1536 gemm1 ids (BN=32)
constexpr int G2 = MT_MAX * 64;            // 3072 gemm2 ids (BN=32)

typedef __attribute__((ext_vector_type(8))) short bf16x8;
typedef __attribute__((ext_vector_type(4))) float f32x4;

__device__ inline unsigned short f2bf(float f) {
  unsigned u = __builtin_bit_cast(unsigned, f);
  u = (u + 0x7FFFu + ((u >> 16) & 1u)) >> 16;
  return (unsigned short)u;
}

__device__ inline bf16x8 pack8(f32x4 a, f32x4 b) {
  bf16x8 v;
  v[0] = (short)f2bf(a[0]); v[1] = (short)f2bf(a[1]);
  v[2] = (short)f2bf(a[2]); v[3] = (short)f2bf(a[3]);
  v[4] = (short)f2bf(b[0]); v[5] = (short)f2bf(b[1]);
  v[6] = (short)f2bf(b[2]); v[7] = (short)f2bf(b[3]);
  return v;
}

// LDS rows of 64 bf16 (128B); XOR swizzle (0 bank conflicts, verified r2-r10)
__device__ inline void st8(unsigned short* s, int r, int c, bf16x8 v) {
  int byte = ((r << 6) + c) * 2;
  byte ^= (r & 7) << 4;
  *reinterpret_cast<bf16x8*>(reinterpret_cast<char*>(s) + byte) = v;
}
__device__ inline bf16x8 ld8(const unsigned short* s, int r, int c) {
  int byte = ((r << 6) + c) * 2;
  byte ^= (r & 7) << 4;
  return *reinterpret_cast<const bf16x8*>(reinterpret_cast<const char*>(s) + byte);
}

// ---------------------------------------------------------------------------
// Launch 1: cvt+zero (blocks 0..G_CVT-1) || routing (block G_CVT)
// pairs sorted by (expert, lora) for L2 locality; tiles at BM=64
// ---------------------------------------------------------------------------
__global__ __launch_bounds__(256) void prep_kernel(
    const float* __restrict__ x, unsigned short* __restrict__ xb,
    float* __restrict__ out,
    const int* __restrict__ topk_ids, const float* __restrict__ topk_w,
    const int* __restrict__ lora_idx,
    int* __restrict__ eoff, int* __restrict__ pair_t,
    float* __restrict__ pair_w, int* __restrict__ pair_e,
    int* __restrict__ tile_e, int* __restrict__ tile_m0, int* __restrict__ ntiles) {
  const int tid = threadIdx.x;
  if (blockIdx.x < G_CVT) {
    const int i = (blockIdx.x * 256 + tid) * 8;
    f32x4 a = *reinterpret_cast<const f32x4*>(x + i);
    f32x4 b = *reinterpret_cast<const f32x4*>(x + i + 4);
    *reinterpret_cast<bf16x8*>(xb + i) = pack8(a, b);
    const f32x4 z = {0.f, 0.f, 0.f, 0.f};
    *reinterpret_cast<f32x4*>(out + i) = z;
    *reinterpret_cast<f32x4*>(out + i + 4) = z;
    return;
  }
  // routing block: (e,l)-bucket count, prefix, scatter
  __shared__ int cnt2[E * L];
  __shared__ int off2[E * L + 1];
  __shared__ int cur2[E * L];
  if (tid < E * L) cnt2[tid] = 0;
  __syncthreads();
  for (int p = tid; p < P; p += 256) {
    const int e = topk_ids[p];
    int l = lora_idx[p / K];
    if (l < 0) l = 0;                      // bucket only; correctness unaffected
    atomicAdd(&cnt2[e * L + l], 1);
  }
  __syncthreads();
  if (tid == 0) {
    off2[0] = 0;
    for (int b = 0; b < E * L; ++b) off2[b + 1] = off2[b] + cnt2[b];
    int nt = 0;
    for (int e = 0; e < E; ++e) {
      const int c = off2[(e + 1) * L] - off2[e * L];
      for (int m0 = 0; m0 < c; m0 += 64) {   // BM=64 tiles
        tile_e[nt] = e;
        tile_m0[nt] = m0;
        ++nt;
      }
    }
    *ntiles = nt;
  }
  __syncthreads();
  if (tid < E * L) cur2[tid] = off2[tid];
  if (tid <= E) eoff[tid] = off2[tid * L];
  __syncthreads();
  for (int p = tid; p < P; p += 256) {
    const int e = topk_ids[p];
    int l = lora_idx[p / K];
    if (l < 0) l = 0;
    const int pos = atomicAdd(&cur2[e * L + l], 1);
    pair_t[pos] = p / K;
    pair_w[pos] = topk_w[p];
    pair_e[pos] = e;
  }
}

// ---------------------------------------------------------------------------
// Launch 2: gemm1 (ids 0..G1-1, BM=64 x BN=32 x BK=64) || lora (G1..G1+P-1)
// 16KB LDS -> ~10 blocks/CU for deep latency hiding
// ---------------------------------------------------------------------------
__global__ __launch_bounds__(256) void gemm1_lora(
    const unsigned short* __restrict__ xb, const float* __restrict__ w1,
    const int* __restrict__ eoff, const int* __restrict__ pair_t,
    const int* __restrict__ tile_e, const int* __restrict__ tile_m0,
    const int* __restrict__ ntiles, unsigned short* __restrict__ act,
    const float* __restrict__ x, const float* __restrict__ lora_a,
    const float* __restrict__ lora_b, const int* __restrict__ lora_idx,
    const int* __restrict__ lora_ranks, const float* __restrict__ scalings,
    const int* __restrict__ pair_e, float* __restrict__ out) {
  __shared__ __align__(16) char smem[16384];
  const int tid = threadIdx.x;

  if (blockIdx.x < (unsigned)G1) {
    // ---- gemm1 tile: BM=64 x BN=32 x BK=64 ----
    const int bid = blockIdx.x;
    const int mt = bid >> 5;
    if (mt >= *ntiles) return;
    const int it = bid & 31;
    const int e = tile_e[mt];
    const int m0 = tile_m0[mt];
    const int beg = eoff[e];
    const int cnt = eoff[e + 1] - beg;
    const int i0 = it * 32;

    unsigned short* sX = (unsigned short*)smem;            // 64x64 = 8KB
    unsigned short* sG = (unsigned short*)(smem + 8192);   // 32x64 = 4KB
    unsigned short* sU = (unsigned short*)(smem + 12288);  // 32x64 = 4KB

    const int xr = tid >> 2, xc = (tid & 3) * 16;   // 4 thr/row, 16 cols each
    const int gr = tid >> 3, gc = (tid & 7) * 8;    // 8 thr/row, 8 cols each

    const int rm = m0 + xr;
    const int tok = (rm < cnt) ? pair_t[beg + rm] : -1;
    const unsigned short* xrow = xb + (size_t)(tok < 0 ? 0 : tok) * H + xc;
    const float* grow = w1 + ((size_t)e * (2 * I) + i0 + gr) * H + gc;
    const float* urow = grow + (size_t)I * H;

    const int lane = tid & 63, wid = tid >> 6;
    const int wm = wid << 4;                 // wave owns rows [wm, wm+16)
    const int fr = lane & 15, fq = lane >> 4;

    f32x4 ag[2], au[2];
#pragma unroll
    for (int b = 0; b < 2; ++b) {
      ag[b] = {0.f, 0.f, 0.f, 0.f};
      au[b] = {0.f, 0.f, 0.f, 0.f};
    }

    bf16x8 rx[2];
    f32x4 rg[2], ru[2];
    const bf16x8 zero8 = {0, 0, 0, 0, 0, 0, 0, 0};

    auto LOAD = [&](int kk) {
      if (tok >= 0) {
        rx[0] = *reinterpret_cast<const bf16x8*>(xrow + kk);
        rx[1] = *reinterpret_cast<const bf16x8*>(xrow + kk + 8);
      } else {
        rx[0] = zero8; rx[1] = zero8;
      }
      rg[0] = *reinterpret_cast<const f32x4*>(grow + kk);
      rg[1] = *reinterpret_cast<const f32x4*>(grow + kk + 4);
      ru[0] = *reinterpret_cast<const f32x4*>(urow + kk);
      ru[1] = *reinterpret_cast<const f32x4*>(urow + kk + 4);
    };

    constexpr int NT = H / 64;
    LOAD(0);
    for (int t = 0; t < NT; ++t) {
      const bf16x8 wg = pack8(rg[0], rg[1]);
      const bf16x8 wu = pack8(ru[0], ru[1]);
      __syncthreads();
      st8(sX, xr, xc, rx[0]); st8(sX, xr, xc + 8, rx[1]);
      st8(sG, gr, gc, wg);
      st8(sU, gr, gc, wu);
      if (t + 1 < NT) LOAD((t + 1) * 64);
      __syncthreads();
#pragma unroll
      for (int kb = 0; kb < 2; ++kb) {
        const int k8 = (kb << 5) + (fq << 3);
        bf16x8 af = ld8(sX, wm + fr, k8);
        bf16x8 gf[2], uf[2];
#pragma unroll
        for (int nj = 0; nj < 2; ++nj) {
          gf[nj] = ld8(sG, (nj << 4) + fr, k8);
          uf[nj] = ld8(sU, (nj << 4) + fr, k8);
        }
#pragma unroll
        for (int nj = 0; nj < 2; ++nj) {
          ag[nj] = __builtin_amdgcn_mfma_f32_16x16x32_bf16(af, gf[nj], ag[nj], 0, 0, 0);
          au[nj] = __builtin_amdgcn_mfma_f32_16x16x32_bf16(af, uf[nj], au[nj], 0, 0, 0);
        }
      }
    }

    // epilogue (C/D: col=lane&15, row=(lane>>4)*4+q)
#pragma unroll
    for (int q = 0; q < 4; ++q) {
      const int m = m0 + wm + (fq << 2) + q;
      if (m >= cnt) continue;
#pragma unroll
      for (int nj = 0; nj < 2; ++nj) {
        const float g = ag[nj][q];
        const float u = au[nj][q];
        const float s = g / (1.f + __expf(-g));
        act[(size_t)(beg + m) * I + i0 + (nj << 4) + fr] = f2bf(s * u);
      }
    }
    return;
  }

  // ---- lora pair ----
  const int p = blockIdx.x - G1;
  const int t = pair_t[p];
  const int e = pair_e[p];
  const int l = lora_idx[t];
  if (l < 0) return;
  int rank = lora_ranks[l];
  if (rank < 1) rank = 1;
  const float sc = scalings[l];

  float* a_sh = (float*)smem;
  const int wave = tid >> 6, lane = tid & 63;
  const float4* xv = reinterpret_cast<const float4*>(x + (size_t)t * H);
  const float* Ab = lora_a + (size_t)(l * E + e) * R * H;
#pragma unroll
  for (int q = 0; q < 4; ++q) {
    const int r = (wave << 2) | q;
    const float4* Av = reinterpret_cast<const float4*>(Ab + (size_t)r * H);
    float s = 0.f;
#pragma unroll
    for (int it2 = 0; it2 < H / 256; ++it2) {
      const int h4 = it2 * 64 + lane;
      const float4 xx = xv[h4];
      const float4 aa = Av[h4];
      s += xx.x * aa.x + xx.y * aa.y + xx.z * aa.z + xx.w * aa.w;
    }
#pragma unroll
    for (int off = 32; off; off >>= 1) s += __shfl_xor(s, off);
    if (lane == 0) a_sh[r] = (r < rank) ? s * sc : 0.f;
  }
  __syncthreads();
  const float* Bb = lora_b + (size_t)(l * E + e) * H * R;
  for (int h = tid; h < H; h += 256) {
    const float4* Bv = reinterpret_cast<const float4*>(Bb + (size_t)h * R);
    float d = 0.f;
#pragma unroll
    for (int r4 = 0; r4 < 4; ++r4) {
      const float4 bb = Bv[r4];
      d += a_sh[r4 * 4 + 0] * bb.x + a_sh[r4 * 4 + 1] * bb.y +
           a_sh[r4 * 4 + 2] * bb.z + a_sh[r4 * 4 + 3] * bb.w;
    }
    atomicAdd(out + (size_t)t * H + h, d);
  }
}

// ---------------------------------------------------------------------------
// Launch 3: gemm2, BM=64 x BN=32 x BK=64; bid = mt*64 + ht; 12KB LDS
// ---------------------------------------------------------------------------
__global__ __launch_bounds__(256) void gemm2_mfma(
    const unsigned short* __restrict__ act, const float* __restrict__ w2,
    const int* __restrict__ eoff, const int* __restrict__ pair_t,
    const float* __restrict__ pair_w, const int* __restrict__ tile_e,
    const int* __restrict__ tile_m0, const int* __restrict__ ntiles,
    float* __restrict__ out) {
  const int bid = blockIdx.x;
  const int mt = bid >> 6;
  if (mt >= *ntiles) return;
  const int ht = bid & 63;
  const int e = tile_e[mt];
  const int m0 = tile_m0[mt];
  const int beg = eoff[e];
  const int cnt = eoff[e + 1] - beg;
  const int h0 = ht * 32;

  __shared__ unsigned short sA[64 * 64];   // 8KB
  __shared__ unsigned short sB[32 * 64];   // 4KB

  const int tid = threadIdx.x;
  const int ar = tid >> 2, ac = (tid & 3) * 16;
  const int br = tid >> 3, bc = (tid & 7) * 8;

  const bool av = (m0 + ar) < cnt;
  const unsigned short* arow = act + (size_t)(beg + (av ? m0 + ar : 0)) * I + ac;
  const float* brow = w2 + ((size_t)e * H + h0 + br) * I + bc;

  const int lane = tid & 63, wid = tid >> 6;
  const int wm = wid << 4;
  const int fr = lane & 15, fq = lane >> 4;

  f32x4 acc[2];
#pragma unroll
  for (int b = 0; b < 2; ++b) acc[b] = {0.f, 0.f, 0.f, 0.f};

  bf16x8 ra[2];
  f32x4 rb[2];

  auto LOAD = [&](int kk) {
    ra[0] = *reinterpret_cast<const bf16x8*>(arow + kk);
    ra[1] = *reinterpret_cast<const bf16x8*>(arow + kk + 8);
    rb[0] = *reinterpret_cast<const f32x4*>(brow + kk);
    rb[1] = *reinterpret_cast<const f32x4*>(brow + kk + 4);
  };

  constexpr int NT2 = I / 64;
  LOAD(0);
  for (int t = 0; t < NT2; ++t) {
    const bf16x8 wb = pack8(rb[0], rb[1]);
    __syncthreads();
    st8(sA, ar, ac, ra[0]); st8(sA, ar, ac + 8, ra[1]);
    st8(sB, br, bc, wb);
    if (t + 1 < NT2) LOAD((t + 1) * 64);
    __syncthreads();
#pragma unroll
    for (int kb = 0; kb < 2; ++kb) {
      const int k8 = (kb << 5) + (fq << 3);
      bf16x8 af = ld8(sA, wm + fr, k8);
      bf16x8 bf[2];
#pragma unroll
      for (int nj = 0; nj < 2; ++nj) bf[nj] = ld8(sB, (nj << 4) + fr, k8);
#pragma unroll
      for (int nj = 0; nj < 2; ++nj)
        acc[nj] = __builtin_amdgcn_mfma_f32_16x16x32_bf16(af, bf[nj], acc[nj], 0, 0, 0);
    }
  }

#pragma unroll
  for (int q = 0; q < 4; ++q) {
    const int m = m0 + wm + (fq << 2) + q;
    if (m >= cnt) continue;
    const int tt = pair_t[beg + m];
    const float w = pair_w[beg + m];
#pragma unroll
    for (int nj = 0; nj < 2; ++nj)
      atomicAdd(out + (size_t)tt * H + h0 + (nj << 4) + fr, w * acc[nj][q]);
  }
}

extern "C" void kernel_launch(void* const* d_in, const int* in_sizes, int n_in,
                              void* d_out, int out_size, void* d_ws, size_t ws_size,
                              hipStream_t stream) {
  const float* x          = (const float*)d_in[0];
  const int*   topk_ids   = (const int*)d_in[1];
  const float* topk_w     = (const float*)d_in[2];
  const int*   lora_idx   = (const int*)d_in[3];
  const int*   lora_ranks = (const int*)d_in[4];
  const float* scalings   = (const float*)d_in[5];
  const float* w1         = (const float*)d_in[6];
  const float* w2         = (const float*)d_in[7];
  const float* lora_a     = (const float*)d_in[8];
  const float* lora_b     = (const float*)d_in[9];
  float* out = (float*)d_out;

  char* ws = (char*)d_ws;
  int*   eoff    = (int*)(ws);             // 17 ints
  int*   ntiles  = (int*)(ws + 96);        // 1 int
  int*   tile_e  = (int*)(ws + 256);       // 48 ints (192B)
  int*   tile_m0 = (int*)(ws + 512);       // 48 ints (192B)
  int*   pair_t  = (int*)(ws + 1024);
  int*   pair_e  = (int*)(ws + 1024 + 4 * P);
  float* pair_w  = (float*)(ws + 1024 + 8 * P);
  unsigned short* xb  = (unsigned short*)(ws + 32768);                      // 4MB
  unsigned short* act = (unsigned short*)(ws + 32768 + (size_t)T * H * 2);  // 4MB

  prep_kernel<<<G_CVT + 1, 256, 0, stream>>>(x, xb, out, topk_ids, topk_w, lora_idx,
                                             eoff, pair_t, pair_w, pair_e, tile_e,
                                             tile_m0, ntiles);
  gemm1_lora<<<G1 + P, 256, 0, stream>>>(xb, w1, eoff, pair_t, tile_e, tile_m0, ntiles,
                                         act, x, lora_a, lora_b, lora_idx, lora_ranks,
                                         scalings, pair_e, out);
  gemm2_mfma<<<G2, 256, 0, stream>>>(act, w2, eoff, pair_t, pair_w, tile_e, tile_m0,
                                     ntiles, out);
}